// Round 13
// baseline (145.783 us; speedup 1.0000x reference)
//
#include <hip/hip_runtime.h>

// MaskAttention: B=4, C=128, H=W=64 -> N=4096
// Round 13: two independent barrier domains (TQ=32, 256thr, grid 512 -> 2 blk/CU,
// pool 37.4KB) + VALU diet (C-init=-FM, v_perm trunc-pack P). Fixed-M softmax,
// P-in-registers, K/V gload_lds double-buffer, plain-sum kj merge, fused LN.

#define CCH 128
#define NTOK 4096
#define FM 16.0f

typedef __attribute__((ext_vector_type(8))) short  bf16x8;
typedef __attribute__((ext_vector_type(4))) short  bf16x4;
typedef __attribute__((ext_vector_type(4))) float  f32x4;

__device__ __forceinline__ f32x4 mfma16(bf16x4 a, bf16x4 b, f32x4 c) {
    return __builtin_amdgcn_mfma_f32_16x16x16bf16_1k(a, b, c, 0, 0, 0);
}

__device__ __forceinline__ unsigned short f2bf(float f) {
    unsigned int u = __builtin_bit_cast(unsigned int, f);
    u += 0x7FFFu + ((u >> 16) & 1u);      // RNE (finite inputs)
    return (unsigned short)(u >> 16);
}
__device__ __forceinline__ unsigned int pack2bf(float a, float b) {
    return (unsigned int)f2bf(a) | ((unsigned int)f2bf(b) << 16);
}
__device__ __forceinline__ void gload_lds16(const void* g, void* l) {
    __builtin_amdgcn_global_load_lds(
        (const __attribute__((address_space(1))) unsigned int*)g,
        (__attribute__((address_space(3))) unsigned int*)l, 16, 0, 0);
}

// ---------------- k1: QKV projections via MFMA (round-5, unchanged) ----------------
__device__ __forceinline__ void stageW(char* Wb, const float* __restrict__ W, int t) {
    const int co = t >> 1, h = t & 1;
    const float4* src = reinterpret_cast<const float4*>(W + co * CCH + h * 64);
    char* row = Wb + co * 256;
    const int sw = (co & 7) << 3;
    #pragma unroll
    for (int q = 0; q < 16; ++q) {
        const float4 v = src[q];
        const int c2 = h * 32 + q * 2;
        *reinterpret_cast<unsigned int*>(row + (((c2    ) ^ sw) << 2)) = pack2bf(v.x, v.y);
        *reinterpret_cast<unsigned int*>(row + (((c2 + 1) ^ sw) << 2)) = pack2bf(v.z, v.w);
    }
}

__global__ __launch_bounds__(256) void qkv_kernel(
    const float* __restrict__ prompt, const float* __restrict__ xg,
    const float* __restrict__ Wq, const float* __restrict__ bq,
    const float* __restrict__ Wk, const float* __restrict__ bk,
    const float* __restrict__ Wv, const float* __restrict__ bv,
    unsigned short* __restrict__ Qo, unsigned short* __restrict__ Ko,
    unsigned short* __restrict__ Vo)
{
    extern __shared__ __align__(16) char qpool[];
    char* pT = qpool;
    char* xT = qpool + 16384;
    char* Wb = qpool + 32768;

    const int t  = threadIdx.x;
    const int b  = blockIdx.x >> 6;
    const int n0 = (blockIdx.x & 63) << 6;
    const int l  = t & 63;
    const int w  = t >> 6;
    const int g  = l >> 4;
    const int lr = l & 15;

    {
        const int c2 = t & 63, th = t >> 6;
        const float* ps = prompt + (((size_t)b * CCH + 2 * c2) << 12) + n0 + th * 16;
        const float* xs = xg     + (((size_t)b * CCH + 2 * c2) << 12) + n0 + th * 16;
        float pa[16], pb[16], xa[16], xb[16];
        #pragma unroll
        for (int q = 0; q < 4; ++q) {
            *reinterpret_cast<float4*>(&pa[q*4]) = *reinterpret_cast<const float4*>(ps + q*4);
            *reinterpret_cast<float4*>(&pb[q*4]) = *reinterpret_cast<const float4*>(ps + 4096 + q*4);
            *reinterpret_cast<float4*>(&xa[q*4]) = *reinterpret_cast<const float4*>(xs + q*4);
            *reinterpret_cast<float4*>(&xb[q*4]) = *reinterpret_cast<const float4*>(xs + 4096 + q*4);
        }
        #pragma unroll
        for (int j = 0; j < 16; ++j) {
            const int tok = th * 16 + j;
            const int off = tok * 256 + (((c2) ^ ((tok & 7) << 3)) << 2);
            *reinterpret_cast<unsigned int*>(pT + off) = pack2bf(pa[j], pb[j]);
            *reinterpret_cast<unsigned int*>(xT + off) = pack2bf(xa[j], xb[j]);
        }
    }
    stageW(Wb, Wq, t);
    __syncthreads();

    const float SC2 = 0.12754849f;   // log2(e)/sqrt(128)
    const int swl = (lr & 7) << 3;

    {   // phase Q
        bf16x8 af[4];
        #pragma unroll
        for (int s = 0; s < 4; ++s)
            af[s] = *reinterpret_cast<const bf16x8*>(
                pT + (w * 16 + lr) * 256 + (((s * 16 + g * 4) ^ swl) << 2));
        f32x4 acc[8];
        #pragma unroll
        for (int cf = 0; cf < 8; ++cf) acc[cf] = (f32x4){0.f,0.f,0.f,0.f};
        #pragma unroll
        for (int cf = 0; cf < 8; ++cf)
            #pragma unroll
            for (int s = 0; s < 4; ++s) {
                bf16x8 bf = *reinterpret_cast<const bf16x8*>(
                    Wb + (cf * 16 + lr) * 256 + (((s * 16 + g * 4) ^ swl) << 2));
                acc[cf] = __builtin_amdgcn_mfma_f32_16x16x32_bf16(af[s], bf, acc[cf], 0, 0, 0);
            }
        #pragma unroll
        for (int cf = 0; cf < 8; ++cf) {
            const float bb = bq[cf * 16 + lr];
            #pragma unroll
            for (int i = 0; i < 4; ++i) {
                const int tok = w * 16 + g * 4 + i;
                Qo[((size_t)(b * NTOK + n0 + tok) << 7) + cf * 16 + lr] =
                    f2bf((acc[cf][i] + bb) * SC2);
            }
        }
    }
    __syncthreads();
    stageW(Wb, Wk, t);
    __syncthreads();

    bf16x8 af[4];
    #pragma unroll
    for (int s = 0; s < 4; ++s)
        af[s] = *reinterpret_cast<const bf16x8*>(
            xT + (w * 16 + lr) * 256 + (((s * 16 + g * 4) ^ swl) << 2));
    {   // phase K
        f32x4 acc[8];
        #pragma unroll
        for (int cf = 0; cf < 8; ++cf) acc[cf] = (f32x4){0.f,0.f,0.f,0.f};
        #pragma unroll
        for (int cf = 0; cf < 8; ++cf)
            #pragma unroll
            for (int s = 0; s < 4; ++s) {
                bf16x8 bf = *reinterpret_cast<const bf16x8*>(
                    Wb + (cf * 16 + lr) * 256 + (((s * 16 + g * 4) ^ swl) << 2));
                acc[cf] = __builtin_amdgcn_mfma_f32_16x16x32_bf16(af[s], bf, acc[cf], 0, 0, 0);
            }
        #pragma unroll
        for (int cf = 0; cf < 8; ++cf) {
            const float bb = bk[cf * 16 + lr];
            #pragma unroll
            for (int i = 0; i < 4; ++i) {
                const int tok = w * 16 + g * 4 + i;
                Ko[((size_t)(b * NTOK + n0 + tok) << 7) + cf * 16 + lr] =
                    f2bf(acc[cf][i] + bb);
            }
        }
    }
    __syncthreads();
    stageW(Wb, Wv, t);
    __syncthreads();

    {   // phase V (transposed store)
        f32x4 acc[8];
        #pragma unroll
        for (int cf = 0; cf < 8; ++cf) acc[cf] = (f32x4){0.f,0.f,0.f,0.f};
        #pragma unroll
        for (int cf = 0; cf < 8; ++cf)
            #pragma unroll
            for (int s = 0; s < 4; ++s) {
                bf16x8 bf = *reinterpret_cast<const bf16x8*>(
                    Wb + (cf * 16 + lr) * 256 + (((s * 16 + g * 4) ^ swl) << 2));
                acc[cf] = __builtin_amdgcn_mfma_f32_16x16x32_bf16(af[s], bf, acc[cf], 0, 0, 0);
            }
        #pragma unroll
        for (int cf = 0; cf < 8; ++cf) {
            const float bb = bv[cf * 16 + lr];
            unsigned short pk[4];
            #pragma unroll
            for (int i = 0; i < 4; ++i) pk[i] = f2bf(acc[cf][i] + bb);
            *reinterpret_cast<unsigned long long*>(
                Vo + (((size_t)(b * CCH + cf * 16 + lr)) << 12) + n0 + w * 16 + g * 4) =
                *reinterpret_cast<unsigned long long*>(pk);
        }
    }
}

// ---------------- k2: attention ----------------
// TQ=32, grid 512 (2 blocks/CU), 256 thr = 4 waves: qd = wq&1 (16 q-rows),
// kj = wq>>1 (16-key half of each 32-key tile). 128 iters. Dynamic LDS 37376:
//   Ks dbuf [0,16384)   2 x 8KB (32 rows x 256B, 16B-chunk ^ (row&7))
//   Vs dbuf [16384,32768) 2 x 8KB (128 ch-rows x 64B, 16B-chunk ^ (row&3))
//   epilogue reuse: mrg [0,18944) = [2 qd][64 l][37 f32]; xstg @18944 [128][36] f32
__device__ __forceinline__ void stage32(
    const unsigned short* __restrict__ Kg, const unsigned short* __restrict__ Vg,
    char* KsB, char* VsB, int b, int m0, int wq, int l)
{
    #pragma unroll
    for (int ii = 0; ii < 2; ++ii) {        // K: 2 x 1KB chunks (4 rows each)
        const int i = wq * 2 + ii;
        const int r = i * 4 + (l >> 4);
        const int csrc = (l & 15) ^ (r & 7);
        gload_lds16(Kg + ((size_t)(b * NTOK + m0 + r) << 7) + csrc * 8, KsB + i * 1024);
    }
    #pragma unroll
    for (int ii = 0; ii < 2; ++ii) {        // V: 2 x 1KB chunks (16 rows each)
        const int i = wq * 2 + ii;
        const int r = i * 16 + (l >> 2);
        const int csrc = (l & 3) ^ (r & 3);
        gload_lds16(Vg + ((size_t)(b * CCH + r) << 12) + m0 + csrc * 8, VsB + i * 1024);
    }
}

__device__ __forceinline__ void attn_phase(
    const unsigned short* __restrict__ Kg, const unsigned short* __restrict__ Vg,
    const int* __restrict__ mb,
    const char* KsCur, const char* VsCur, char* KsNxt, char* VsNxt,
    int b, int m0, int mnext, int wq, int l, int kj, int g, int lr,
    const bf16x8 (&qf)[4], f32x4 (&acc)[8], float& lrun)
{
    __builtin_amdgcn_s_barrier();            // [A] prev compute reads done
    __builtin_amdgcn_sched_barrier(0);

    const int4 mv = *reinterpret_cast<const int4*>(mb + m0 + kj * 16 + g * 4);
    stage32(Kg, Vg, KsNxt, VsNxt, b, mnext, wq, l);

    asm volatile("s_waitcnt vmcnt(5)" ::: "memory");  // this tile's stage drained
    __builtin_amdgcn_sched_barrier(0);
    __builtin_amdgcn_s_barrier();            // [B] tile visible
    __builtin_amdgcn_sched_barrier(0);

    // ---- S^T = mfma(K, Q) with C-init = -FM ----
    f32x4 sf = (f32x4){-FM, -FM, -FM, -FM};
    const char* rp = KsCur + (kj * 16 + lr) * 256;
    const int swz = (lr & 7) << 4;
    #pragma unroll
    for (int s = 0; s < 4; ++s) {
        bf16x8 kb = *reinterpret_cast<const bf16x8*>(rp + ((s * 64 + g * 16) ^ swz));
        sf = __builtin_amdgcn_mfma_f32_16x16x32_bf16(kb, qf[s], sf, 0, 0, 0);
    }

    // ---- fixed-M softmax, trunc-pack P via v_perm ----
    const float p0 = mv.x ? exp2f(sf[0]) : 0.f;
    const float p1 = mv.y ? exp2f(sf[1]) : 0.f;
    const float p2 = mv.z ? exp2f(sf[2]) : 0.f;
    const float p3 = mv.w ? exp2f(sf[3]) : 0.f;
    lrun += (p0 + p1) + (p2 + p3);
    const unsigned w0 = __builtin_amdgcn_perm(
        __builtin_bit_cast(unsigned, p1), __builtin_bit_cast(unsigned, p0), 0x07060302u);
    const unsigned w1 = __builtin_amdgcn_perm(
        __builtin_bit_cast(unsigned, p3), __builtin_bit_cast(unsigned, p2), 0x07060302u);
    const unsigned long long pk = (unsigned long long)w0 | ((unsigned long long)w1 << 32);
    const bf16x4 pb = __builtin_bit_cast(bf16x4, pk);

    // ---- O^T += mfma16(V, P) ----
    const int voff = (((kj * 2 + (g >> 1)) ^ (lr & 3)) << 4) + ((g & 1) << 3);
    #pragma unroll
    for (int cf = 0; cf < 8; ++cf) {
        const bf16x4 vb = *reinterpret_cast<const bf16x4*>(
            VsCur + (cf * 16 + lr) * 64 + voff);
        acc[cf] = mfma16(vb, pb, acc[cf]);
    }
}

__global__ __launch_bounds__(256) void attn_ln_kernel(
    const unsigned short* __restrict__ Qg, const unsigned short* __restrict__ Kg,
    const unsigned short* __restrict__ Vg,
    const int* __restrict__ maskb, const float* __restrict__ xg,
    const float* __restrict__ gamma, const float* __restrict__ beta,
    float* __restrict__ out)
{
    extern __shared__ __align__(16) char pool[];
    char* Ks0 = pool;
    char* Ks1 = pool + 8192;
    char* Vs0 = pool + 16384;
    char* Vs1 = pool + 24576;
    float* mrg  = (float*)pool;                 // [2 qd][64 l][37]
    float* xstg = (float*)(pool + 18944);       // [128][36]

    // XCD swizzle: batch -> 2 XCDs (K+V 2MB in 8MB of L2)
    const int raw = blockIdx.x;
    const int bid = (raw & 7) * 64 + (raw >> 3);
    const int t  = threadIdx.x;
    const int b  = bid >> 7;
    const int n0 = (bid & 127) << 5;
    const int l  = t & 63;
    const int wq = t >> 6;
    const int qd = wq & 1;        // q half (16 rows)
    const int kj = wq >> 1;       // 16-key half of tile
    const int g  = l >> 4;
    const int lr = l & 15;

    // Q fragments (B-operand): lane holds Q[n0+qd*16+lr][s*32 + g*8 + j]
    bf16x8 qf[4];
    {
        const unsigned short* qp =
            Qg + ((size_t)(b * NTOK + n0 + qd * 16 + lr)) * CCH + g * 8;
        #pragma unroll
        for (int s = 0; s < 4; ++s)
            qf[s] = *reinterpret_cast<const bf16x8*>(qp + s * 32);
    }

    // acc[cf][i] = unnormalized O^T[ch=cf*16+g*4+i][q=qd*16+lr], scale 2^-FM
    f32x4 acc[8];
    float lrun = 0.f;
    #pragma unroll
    for (int cf = 0; cf < 8; ++cf) acc[cf] = (f32x4){0.f,0.f,0.f,0.f};

    const int* mb = maskb + (size_t)b * NTOK;

    stage32(Kg, Vg, Ks0, Vs0, b, 0, wq, l);

    for (int it = 0; it < 128; it += 2) {
        attn_phase(Kg, Vg, mb, Ks0, Vs0, Ks1, Vs1,
                   b, it << 5, ((it + 1) & 127) << 5, wq, l, kj, g, lr, qf, acc, lrun);
        attn_phase(Kg, Vg, mb, Ks1, Vs1, Ks0, Vs0,
                   b, (it + 1) << 5, ((it + 2) & 127) << 5, wq, l, kj, g, lr, qf, acc, lrun);
    }

    // finish per-lane row sums across g
    lrun += __shfl_xor(lrun, 16);
    lrun += __shfl_xor(lrun, 32);

    // ---------------- 2-way kj merge (plain sums) + residual + LN -----------------
    asm volatile("s_waitcnt vmcnt(0)" ::: "memory");   // dangling wrap-stage done
    __syncthreads();

    if (kj == 1) {                       // publish partials: 32 acc + lrun
        float* dst = mrg + (qd * 64 + l) * 37;
        #pragma unroll
        for (int cf = 0; cf < 8; ++cf)
            #pragma unroll
            for (int i = 0; i < 4; ++i) dst[cf * 4 + i] = acc[cf][i];
        dst[32] = lrun;
    }
    {   // stage x tile (c-major, stride 36) — all 256 threads
        const int c = t >> 1, h0 = (t & 1) << 4;
        const float* src = xg + (((size_t)b * CCH + c) << 12) + n0 + h0;
        float* dst = xstg + c * 36 + h0;
        #pragma unroll
        for (int k = 0; k < 16; k += 4) {
            const float4 v = *reinterpret_cast<const float4*>(src + k);
            dst[k] = v.x; dst[k+1] = v.y; dst[k+2] = v.z; dst[k+3] = v.w;
        }
    }
    __syncthreads();

    if (kj == 0) {                       // absorb + residual + LayerNorm
        const float* src = mrg + (qd * 64 + l) * 37;
        float gm[8][4], bt[8][4];
        #pragma unroll
        for (int cf = 0; cf < 8; ++cf)
            #pragma unroll
            for (int i = 0; i < 4; ++i) {
                gm[cf][i] = gamma[cf * 16 + g * 4 + i];
                bt[cf][i] = beta [cf * 16 + g * 4 + i];
            }
        const float inv = 1.f / (lrun + src[32]);
        const int nloc = qd * 16 + lr;
        float sum = 0.f, sq = 0.f;
        #pragma unroll
        for (int cf = 0; cf < 8; ++cf)
            #pragma unroll
            for (int i = 0; i < 4; ++i) {
                const float o = acc[cf][i] + src[cf * 4 + i];
                const float v = o * inv + xstg[(cf * 16 + g * 4 + i) * 36 + nloc];
                acc[cf][i] = v; sum += v; sq += v * v;
            }
        sum += __shfl_xor(sum, 16); sq += __shfl_xor(sq, 16);
        sum += __shfl_xor(sum, 32); sq += __shfl_xor(sq, 32);
        const float mean = sum * (1.f / 128.f);
        const float var  = sq * (1.f / 128.f) - mean * mean;
        const float rstd = rsqrtf(var + 1e-5f);
        #pragma unroll
        for (int cf = 0; cf < 8; ++cf)
            #pragma unroll
            for (int i = 0; i < 4; ++i)
                xstg[(cf * 16 + g * 4 + i) * 36 + nloc] =
                    (acc[cf][i] - mean) * rstd * gm[cf][i] + bt[cf][i];
    }
    __syncthreads();

    {   // coalesced transposed store — all 256 threads
        const int c = t >> 1, h0 = (t & 1) << 4;
        float* dst = out + (((size_t)b * CCH + c) << 12) + n0 + h0;
        const float* srcl = xstg + c * 36 + h0;
        #pragma unroll
        for (int k = 0; k < 16; k += 4) {
            float4 v; v.x = srcl[k]; v.y = srcl[k+1]; v.z = srcl[k+2]; v.w = srcl[k+3];
            *reinterpret_cast<float4*>(dst + k) = v;
        }
    }
}

extern "C" void kernel_launch(void* const* d_in, const int* in_sizes, int n_in,
                              void* d_out, int out_size, void* d_ws, size_t ws_size,
                              hipStream_t stream) {
    const float* prompt = (const float*)d_in[0];
    const float* x      = (const float*)d_in[1];
    const float* Wq     = (const float*)d_in[2];
    const float* bq     = (const float*)d_in[3];
    const float* Wk     = (const float*)d_in[4];
    const float* bk     = (const float*)d_in[5];
    const float* Wv     = (const float*)d_in[6];
    const float* bv     = (const float*)d_in[7];
    const float* gamma  = (const float*)d_in[8];
    const float* beta   = (const float*)d_in[9];
    const int*   maskb  = (const int*)d_in[10];
    float* out = (float*)d_out;

    const size_t M = (size_t)4 * NTOK * CCH;
    unsigned short* Qw = (unsigned short*)d_ws;
    unsigned short* Kw = Qw + M;
    unsigned short* Vw = Kw + M;

    (void)hipFuncSetAttribute((const void*)qkv_kernel,
                              hipFuncAttributeMaxDynamicSharedMemorySize, 65536);
    (void)hipFuncSetAttribute((const void*)attn_ln_kernel,
                              hipFuncAttributeMaxDynamicSharedMemorySize, 37376);

    qkv_kernel<<<256, 256, 65536, stream>>>(prompt, x, Wq, bq, Wk, bk, Wv, bv, Qw, Kw, Vw);
    attn_ln_kernel<<<512, 256, 37376, stream>>>(Qw, Kw, Vw, maskb, x, gamma, beta, out);
}

// Round 14
// 94.503 us; speedup vs baseline: 1.5426x; 1.5426x over previous
//
#include <hip/hip_runtime.h>

// MaskAttention: B=4, C=128, H=W=64 -> N=4096
// Round 14 = round 12 (97 us, best) + VALU diet ONLY:
//   - S^T MFMA C-initializer = -FM (kills the per-key subtract)
//   - P pack via one v_perm_b32 per pair (truncation; numerator-only error 2^-8)
// Everything else byte-identical to r12. (r13's thin-phase/64B-V-row reshape
// regressed: 29M bank conflicts + 4x barrier count — reverted.)

#define CCH 128
#define NTOK 4096
#define FM 16.0f

typedef __attribute__((ext_vector_type(8))) short  bf16x8;
typedef __attribute__((ext_vector_type(4))) short  bf16x4;
typedef __attribute__((ext_vector_type(4))) float  f32x4;

__device__ __forceinline__ f32x4 mfma16(bf16x4 a, bf16x4 b, f32x4 c) {
    return __builtin_amdgcn_mfma_f32_16x16x16bf16_1k(a, b, c, 0, 0, 0);
}

__device__ __forceinline__ unsigned short f2bf(float f) {
    unsigned int u = __builtin_bit_cast(unsigned int, f);
    u += 0x7FFFu + ((u >> 16) & 1u);      // RNE (finite inputs)
    return (unsigned short)(u >> 16);
}
__device__ __forceinline__ unsigned int pack2bf(float a, float b) {
    return (unsigned int)f2bf(a) | ((unsigned int)f2bf(b) << 16);
}
__device__ __forceinline__ void gload_lds16(const void* g, void* l) {
    __builtin_amdgcn_global_load_lds(
        (const __attribute__((address_space(1))) unsigned int*)g,
        (__attribute__((address_space(3))) unsigned int*)l, 16, 0, 0);
}

// ---------------- k1: QKV projections via MFMA (round-5, unchanged) ----------------
__device__ __forceinline__ void stageW(char* Wb, const float* __restrict__ W, int t) {
    const int co = t >> 1, h = t & 1;
    const float4* src = reinterpret_cast<const float4*>(W + co * CCH + h * 64);
    char* row = Wb + co * 256;
    const int sw = (co & 7) << 3;
    #pragma unroll
    for (int q = 0; q < 16; ++q) {
        const float4 v = src[q];
        const int c2 = h * 32 + q * 2;
        *reinterpret_cast<unsigned int*>(row + (((c2    ) ^ sw) << 2)) = pack2bf(v.x, v.y);
        *reinterpret_cast<unsigned int*>(row + (((c2 + 1) ^ sw) << 2)) = pack2bf(v.z, v.w);
    }
}

__global__ __launch_bounds__(256) void qkv_kernel(
    const float* __restrict__ prompt, const float* __restrict__ xg,
    const float* __restrict__ Wq, const float* __restrict__ bq,
    const float* __restrict__ Wk, const float* __restrict__ bk,
    const float* __restrict__ Wv, const float* __restrict__ bv,
    unsigned short* __restrict__ Qo, unsigned short* __restrict__ Ko,
    unsigned short* __restrict__ Vo)
{
    extern __shared__ __align__(16) char qpool[];
    char* pT = qpool;
    char* xT = qpool + 16384;
    char* Wb = qpool + 32768;

    const int t  = threadIdx.x;
    const int b  = blockIdx.x >> 6;
    const int n0 = (blockIdx.x & 63) << 6;
    const int l  = t & 63;
    const int w  = t >> 6;
    const int g  = l >> 4;
    const int lr = l & 15;

    {
        const int c2 = t & 63, th = t >> 6;
        const float* ps = prompt + (((size_t)b * CCH + 2 * c2) << 12) + n0 + th * 16;
        const float* xs = xg     + (((size_t)b * CCH + 2 * c2) << 12) + n0 + th * 16;
        float pa[16], pb[16], xa[16], xb[16];
        #pragma unroll
        for (int q = 0; q < 4; ++q) {
            *reinterpret_cast<float4*>(&pa[q*4]) = *reinterpret_cast<const float4*>(ps + q*4);
            *reinterpret_cast<float4*>(&pb[q*4]) = *reinterpret_cast<const float4*>(ps + 4096 + q*4);
            *reinterpret_cast<float4*>(&xa[q*4]) = *reinterpret_cast<const float4*>(xs + q*4);
            *reinterpret_cast<float4*>(&xb[q*4]) = *reinterpret_cast<const float4*>(xs + 4096 + q*4);
        }
        #pragma unroll
        for (int j = 0; j < 16; ++j) {
            const int tok = th * 16 + j;
            const int off = tok * 256 + (((c2) ^ ((tok & 7) << 3)) << 2);
            *reinterpret_cast<unsigned int*>(pT + off) = pack2bf(pa[j], pb[j]);
            *reinterpret_cast<unsigned int*>(xT + off) = pack2bf(xa[j], xb[j]);
        }
    }
    stageW(Wb, Wq, t);
    __syncthreads();

    const float SC2 = 0.12754849f;   // log2(e)/sqrt(128)
    const int swl = (lr & 7) << 3;

    {   // phase Q
        bf16x8 af[4];
        #pragma unroll
        for (int s = 0; s < 4; ++s)
            af[s] = *reinterpret_cast<const bf16x8*>(
                pT + (w * 16 + lr) * 256 + (((s * 16 + g * 4) ^ swl) << 2));
        f32x4 acc[8];
        #pragma unroll
        for (int cf = 0; cf < 8; ++cf) acc[cf] = (f32x4){0.f,0.f,0.f,0.f};
        #pragma unroll
        for (int cf = 0; cf < 8; ++cf)
            #pragma unroll
            for (int s = 0; s < 4; ++s) {
                bf16x8 bf = *reinterpret_cast<const bf16x8*>(
                    Wb + (cf * 16 + lr) * 256 + (((s * 16 + g * 4) ^ swl) << 2));
                acc[cf] = __builtin_amdgcn_mfma_f32_16x16x32_bf16(af[s], bf, acc[cf], 0, 0, 0);
            }
        #pragma unroll
        for (int cf = 0; cf < 8; ++cf) {
            const float bb = bq[cf * 16 + lr];
            #pragma unroll
            for (int i = 0; i < 4; ++i) {
                const int tok = w * 16 + g * 4 + i;
                Qo[((size_t)(b * NTOK + n0 + tok) << 7) + cf * 16 + lr] =
                    f2bf((acc[cf][i] + bb) * SC2);
            }
        }
    }
    __syncthreads();
    stageW(Wb, Wk, t);
    __syncthreads();

    bf16x8 af[4];
    #pragma unroll
    for (int s = 0; s < 4; ++s)
        af[s] = *reinterpret_cast<const bf16x8*>(
            xT + (w * 16 + lr) * 256 + (((s * 16 + g * 4) ^ swl) << 2));
    {   // phase K
        f32x4 acc[8];
        #pragma unroll
        for (int cf = 0; cf < 8; ++cf) acc[cf] = (f32x4){0.f,0.f,0.f,0.f};
        #pragma unroll
        for (int cf = 0; cf < 8; ++cf)
            #pragma unroll
            for (int s = 0; s < 4; ++s) {
                bf16x8 bf = *reinterpret_cast<const bf16x8*>(
                    Wb + (cf * 16 + lr) * 256 + (((s * 16 + g * 4) ^ swl) << 2));
                acc[cf] = __builtin_amdgcn_mfma_f32_16x16x32_bf16(af[s], bf, acc[cf], 0, 0, 0);
            }
        #pragma unroll
        for (int cf = 0; cf < 8; ++cf) {
            const float bb = bk[cf * 16 + lr];
            #pragma unroll
            for (int i = 0; i < 4; ++i) {
                const int tok = w * 16 + g * 4 + i;
                Ko[((size_t)(b * NTOK + n0 + tok) << 7) + cf * 16 + lr] =
                    f2bf(acc[cf][i] + bb);
            }
        }
    }
    __syncthreads();
    stageW(Wb, Wv, t);
    __syncthreads();

    {   // phase V (transposed store)
        f32x4 acc[8];
        #pragma unroll
        for (int cf = 0; cf < 8; ++cf) acc[cf] = (f32x4){0.f,0.f,0.f,0.f};
        #pragma unroll
        for (int cf = 0; cf < 8; ++cf)
            #pragma unroll
            for (int s = 0; s < 4; ++s) {
                bf16x8 bf = *reinterpret_cast<const bf16x8*>(
                    Wb + (cf * 16 + lr) * 256 + (((s * 16 + g * 4) ^ swl) << 2));
                acc[cf] = __builtin_amdgcn_mfma_f32_16x16x32_bf16(af[s], bf, acc[cf], 0, 0, 0);
            }
        #pragma unroll
        for (int cf = 0; cf < 8; ++cf) {
            const float bb = bv[cf * 16 + lr];
            unsigned short pk[4];
            #pragma unroll
            for (int i = 0; i < 4; ++i) pk[i] = f2bf(acc[cf][i] + bb);
            *reinterpret_cast<unsigned long long*>(
                Vo + (((size_t)(b * CCH + cf * 16 + lr)) << 12) + n0 + w * 16 + g * 4) =
                *reinterpret_cast<unsigned long long*>(pk);
        }
    }
}

// ---------------- k2: attention (r12 structure) ----------------
// 512 thr = 8 waves: h = wq>>2 (K-range half), kj2 = (wq>>1)&1 (32-key half of
// tile), qh = wq&1 (q half). Dynamic LDS 139264:
//   h0: K dbuf @0 (2x16384), V dbuf @32768 ; h1: K @65536, V @98304
//   epilogue reuse: mrg @0 (6 slots x 64 x 69 f32), stg @105984 (128 x 65 f32)
__device__ __forceinline__ void stage_tile(
    const unsigned short* __restrict__ Kg, const unsigned short* __restrict__ Vg,
    char* KsB, char* VsB, int b, int m0, int w4, int l)
{
    #pragma unroll
    for (int ii = 0; ii < 4; ++ii) {        // K: 4 x 1KB chunks (4 rows each)
        const int i = w4 * 4 + ii;
        const int r = i * 4 + (l >> 4);
        const int csrc = (l & 15) ^ (r & 7);
        const unsigned short* src = Kg + ((size_t)(b * NTOK + m0 + r) << 7) + csrc * 8;
        gload_lds16(src, KsB + i * 1024);
    }
    #pragma unroll
    for (int ii = 0; ii < 4; ++ii) {        // V: 4 x 1KB chunks (8 rows each)
        const int i = w4 * 4 + ii;
        const int r = i * 8 + (l >> 3);
        const int csrc = (l & 7) ^ (r & 7);
        const unsigned short* src = Vg + ((size_t)(b * CCH + r) << 12) + m0 + csrc * 8;
        gload_lds16(src, VsB + i * 1024);
    }
}

__global__ __launch_bounds__(512) void attn_ln_kernel(
    const unsigned short* __restrict__ Qg, const unsigned short* __restrict__ Kg,
    const unsigned short* __restrict__ Vg,
    const int* __restrict__ maskb, const float* __restrict__ xg,
    const float* __restrict__ gamma, const float* __restrict__ beta,
    float* __restrict__ out)
{
    extern __shared__ __align__(16) char pool[];

    // XCD swizzle: batch -> 2 XCDs so K+V (2MB/batch) sits in per-XCD L2.
    const int bid = (blockIdx.x & 7) * 32 + (blockIdx.x >> 3);
    const int t  = threadIdx.x;
    const int b  = bid >> 6;
    const int n0 = (bid & 63) << 6;
    const int l  = t & 63;
    const int wq = t >> 6;
    const int h  = wq >> 2;
    const int kj2 = (wq >> 1) & 1;
    const int qh = wq & 1;
    const int w4 = wq & 3;
    const int g  = l >> 4;
    const int lr = l & 15;
    const int swz = (lr & 7) << 4;
    const int base_m = h << 11;

    char* KsH = pool + h * 65536;
    char* VsH = pool + h * 65536 + 32768;

    // Q fragments (B-operand): lane holds Q[n0+qh*32+rf*16+lr][s*32 + g*8 + j]
    bf16x8 qf[2][4];
    #pragma unroll
    for (int rf = 0; rf < 2; ++rf) {
        const unsigned short* qp =
            Qg + ((size_t)(b * NTOK + n0 + qh * 32 + rf * 16 + lr)) * CCH + g * 8;
        #pragma unroll
        for (int s = 0; s < 4; ++s)
            qf[rf][s] = *reinterpret_cast<const bf16x8*>(qp + s * 32);
    }

    // acc[rf][cf][i] = unnormalized O^T[ch=cf*16+g*4+i][q=qh*32+rf*16+lr], scale 2^-FM
    f32x4 acc[2][8];
    float lrun[2] = {0.f, 0.f};
    #pragma unroll
    for (int rf = 0; rf < 2; ++rf)
        #pragma unroll
        for (int cf = 0; cf < 8; ++cf) acc[rf][cf] = (f32x4){0.f,0.f,0.f,0.f};

    stage_tile(Kg, Vg, KsH, VsH, b, base_m, w4, l);

    for (int it = 0; it < 32; ++it) {
        __builtin_amdgcn_s_barrier();            // [A] prev compute reads done
        __builtin_amdgcn_sched_barrier(0);

        const int m0 = base_m + (it << 6);
        const int4 mv0 = *reinterpret_cast<const int4*>(
            maskb + (size_t)b * NTOK + m0 + kj2 * 32 + g * 4);
        const int4 mv1 = *reinterpret_cast<const int4*>(
            maskb + (size_t)b * NTOK + m0 + kj2 * 32 + 16 + g * 4);

        const int tn = (it + 1) & 31;            // wrap-stage keeps vmcnt math exact
        stage_tile(Kg, Vg, KsH + (tn & 1) * 16384, VsH + (tn & 1) * 16384,
                   b, base_m + (tn << 6), w4, l);

        asm volatile("s_waitcnt vmcnt(10)" ::: "memory");  // stage(it) drained
        __builtin_amdgcn_sched_barrier(0);
        __builtin_amdgcn_s_barrier();            // [B] stage(it) visible
        __builtin_amdgcn_sched_barrier(0);

        const char* Ks_c = KsH + (it & 1) * 16384;
        const char* Vs_c = VsH + (it & 1) * 16384;

        // ---- S^T = mfma(K, Q), C-init = -FM ----
        f32x4 sf[2][2];
        #pragma unroll
        for (int rf = 0; rf < 2; ++rf)
            #pragma unroll
            for (int sub = 0; sub < 2; ++sub)
                sf[rf][sub] = (f32x4){-FM, -FM, -FM, -FM};
        #pragma unroll
        for (int sub = 0; sub < 2; ++sub) {
            const char* rp = Ks_c + (kj2 * 32 + sub * 16 + lr) * 256;
            #pragma unroll
            for (int s = 0; s < 4; ++s) {
                bf16x8 kb = *reinterpret_cast<const bf16x8*>(rp + ((s * 64 + g * 16) ^ swz));
                sf[0][sub] = __builtin_amdgcn_mfma_f32_16x16x32_bf16(kb, qf[0][s], sf[0][sub], 0, 0, 0);
                sf[1][sub] = __builtin_amdgcn_mfma_f32_16x16x32_bf16(kb, qf[1][s], sf[1][sub], 0, 0, 0);
            }
        }

        // ---- fixed-M softmax, trunc-pack P via v_perm ----
        bf16x4 pb[2][2];   // [rf][sub]
        #pragma unroll
        for (int rf = 0; rf < 2; ++rf) {
            #pragma unroll
            for (int sub = 0; sub < 2; ++sub) {
                const int4 mv = sub ? mv1 : mv0;
                const float p0 = mv.x ? exp2f(sf[rf][sub][0]) : 0.f;
                const float p1 = mv.y ? exp2f(sf[rf][sub][1]) : 0.f;
                const float p2 = mv.z ? exp2f(sf[rf][sub][2]) : 0.f;
                const float p3 = mv.w ? exp2f(sf[rf][sub][3]) : 0.f;
                lrun[rf] += (p0 + p1) + (p2 + p3);
                const unsigned w0 = __builtin_amdgcn_perm(
                    __builtin_bit_cast(unsigned, p1), __builtin_bit_cast(unsigned, p0),
                    0x07060302u);
                const unsigned w1 = __builtin_amdgcn_perm(
                    __builtin_bit_cast(unsigned, p3), __builtin_bit_cast(unsigned, p2),
                    0x07060302u);
                const unsigned long long pk =
                    (unsigned long long)w0 | ((unsigned long long)w1 << 32);
                pb[rf][sub] = __builtin_bit_cast(bf16x4, pk);
            }
        }

        // ---- O^T += mfma16(V, P): V b64 from LDS, P from registers ----
        #pragma unroll
        for (int sub = 0; sub < 2; ++sub) {
            const int s16 = kj2 * 2 + sub;   // 16-key slice id in 64-key tile
            #pragma unroll
            for (int cf = 0; cf < 8; ++cf) {
                const bf16x4 vb = *reinterpret_cast<const bf16x4*>(
                    Vs_c + (cf * 16 + lr) * 128 +
                    ((((s16 * 2 + (g >> 1)) ^ (lr & 7)) << 4) + ((g & 1) << 3)));
                acc[0][cf] = mfma16(vb, pb[0][sub], acc[0][cf]);
                acc[1][cf] = mfma16(vb, pb[1][sub], acc[1][cf]);
            }
        }
    }

    // ---------------- 4-way plain-sum merge + residual + LayerNorm + transpose ------
    asm volatile("s_waitcnt vmcnt(0)" ::: "memory");   // dangling wrap-stage done
    #pragma unroll
    for (int rf = 0; rf < 2; ++rf) {     // finish per-lane row sums across g
        lrun[rf] += __shfl_xor(lrun[rf], 16);
        lrun[rf] += __shfl_xor(lrun[rf], 32);
    }
    __syncthreads();

    const int sub4 = wq >> 1;            // (h,kj2) id 0..3
    float* mrg = (float*)pool;
    float* stg = (float*)(pool + 105984);

    if (sub4 != 0) {                     // publish partials, stride 69 floats
        float* dst = mrg + ((sub4 - 1) * 2 + qh) * 4416 + l * 69;
        #pragma unroll
        for (int rf = 0; rf < 2; ++rf)
            #pragma unroll
            for (int cf = 0; cf < 8; ++cf)
                #pragma unroll
                for (int i = 0; i < 4; ++i)
                    dst[rf * 32 + cf * 4 + i] = acc[rf][cf][i];
        dst[64] = lrun[0]; dst[65] = lrun[1];
    }
    {   // stage x tile (c-major, stride 65) — all 512 threads
        const int c = t >> 2, h0 = (t & 3) << 4;
        const float* src = xg + (((size_t)b * CCH + c) << 12) + n0 + h0;
        float* dst = stg + c * 65 + h0;
        #pragma unroll
        for (int k = 0; k < 16; k += 4) {
            const float4 v = *reinterpret_cast<const float4*>(src + k);
            dst[k] = v.x; dst[k+1] = v.y; dst[k+2] = v.z; dst[k+3] = v.w;
        }
    }
    __syncthreads();

    if (sub4 == 0) {
        const float* r1 = mrg + (0 * 2 + qh) * 4416 + l * 69;
        const float* r2 = mrg + (1 * 2 + qh) * 4416 + l * 69;
        const float* r3 = mrg + (2 * 2 + qh) * 4416 + l * 69;
        float gm[8][4], bt[8][4];
        #pragma unroll
        for (int cf = 0; cf < 8; ++cf)
            #pragma unroll
            for (int i = 0; i < 4; ++i) {
                gm[cf][i] = gamma[cf * 16 + g * 4 + i];
                bt[cf][i] = beta [cf * 16 + g * 4 + i];
            }
        #pragma unroll
        for (int rf = 0; rf < 2; ++rf) {
            const float inv = 1.f / (lrun[rf] + r1[64 + rf] + r2[64 + rf] + r3[64 + rf]);
            const int nloc = qh * 32 + rf * 16 + lr;
            float sum = 0.f, sq = 0.f;
            #pragma unroll
            for (int cf = 0; cf < 8; ++cf)
                #pragma unroll
                for (int i = 0; i < 4; ++i) {
                    const int idx = rf * 32 + cf * 4 + i;
                    const float o = acc[rf][cf][i] + r1[idx] + r2[idx] + r3[idx];
                    const float v = o * inv + stg[(cf * 16 + g * 4 + i) * 65 + nloc];
                    acc[rf][cf][i] = v; sum += v; sq += v * v;
                }
            sum += __shfl_xor(sum, 16); sq += __shfl_xor(sq, 16);
            sum += __shfl_xor(sum, 32); sq += __shfl_xor(sq, 32);
            const float mean = sum * (1.f / 128.f);
            const float var  = sq * (1.f / 128.f) - mean * mean;
            const float rstd = rsqrtf(var + 1e-5f);
            #pragma unroll
            for (int cf = 0; cf < 8; ++cf)
                #pragma unroll
                for (int i = 0; i < 4; ++i)
                    stg[(cf * 16 + g * 4 + i) * 65 + nloc] =
                        (acc[rf][cf][i] - mean) * rstd * gm[cf][i] + bt[cf][i];
        }
    }
    __syncthreads();

    {   // coalesced transposed store — all 512 threads
        const int c = t >> 2, h0 = (t & 3) << 4;
        float* dst = out + (((size_t)b * CCH + c) << 12) + n0 + h0;
        const float* srcl = stg + c * 65 + h0;
        #pragma unroll
        for (int k = 0; k < 16; k += 4) {
            float4 v; v.x = srcl[k]; v.y = srcl[k+1]; v.z = srcl[k+2]; v.w = srcl[k+3];
            *reinterpret_cast<float4*>(dst + k) = v;
        }
    }
}

extern "C" void kernel_launch(void* const* d_in, const int* in_sizes, int n_in,
                              void* d_out, int out_size, void* d_ws, size_t ws_size,
                              hipStream_t stream) {
    const float* prompt = (const float*)d_in[0];
    const float* x      = (const float*)d_in[1];
    const float* Wq     = (const float*)d_in[2];
    const float* bq     = (const float*)d_in[3];
    const float* Wk     = (const float*)d_in[4];
    const float* bk     = (const float*)d_in[5];
    const float* Wv     = (const float*)d_in[6];
    const float* bv     = (const float*)d_in[7];
    const float* gamma  = (const float*)d_in[8];
    const float* beta   = (const float*)d_in[9];
    const int*   maskb  = (const int*)d_in[10];
    float* out = (float*)d_out;

    const size_t M = (size_t)4 * NTOK * CCH;
    unsigned short* Qw = (unsigned short*)d_ws;
    unsigned short* Kw = Qw + M;
    unsigned short* Vw = Kw + M;

    (void)hipFuncSetAttribute((const void*)qkv_kernel,
                              hipFuncAttributeMaxDynamicSharedMemorySize, 65536);
    (void)hipFuncSetAttribute((const void*)attn_ln_kernel,
                              hipFuncAttributeMaxDynamicSharedMemorySize, 139264);

    qkv_kernel<<<256, 256, 65536, stream>>>(prompt, x, Wq, bq, Wk, bk, Wv, bv, Qw, Kw, Vw);
    attn_ln_kernel<<<256, 512, 139264, stream>>>(Qw, Kw, Vw, maskb, x, gamma, beta, out);
}